// Round 11
// baseline (159.331 us; speedup 1.0000x reference)
//
#include <hip/hip_runtime.h>
#include <cstdint>

// Dims: B=8, H=128, D=512, L=128, V=2D=1024, inner=384
#define L_ 128

using bf16   = __bf16;
using bf16x2 = __attribute__((ext_vector_type(2))) __bf16;
using bf16x4 = __attribute__((ext_vector_type(4))) __bf16;
using bf16x8 = __attribute__((ext_vector_type(8))) __bf16;
using f32x4  = __attribute__((ext_vector_type(4))) float;

#define MFMA_B16(a, b, c) __builtin_amdgcn_mfma_f32_16x16x32_bf16((a), (b), (c), 0, 0, 0)

// ---------------- Kernel 1: argmax(|d_x|) + gather -> pv bf16 [B,H,V] ----------------
// 32 lanes per row, TWO rows per wave (half = lane>>5), 16 iterations per wave:
// each wave load instruction covers 1016 B contiguous (two adjacent 508-B rows)
// -> fully coalesced; 4096 blocks = 16K waves (good wave economy). 32-lane
// (val,idx) lexicographic butterfly (offsets 1..16 stay within each half-wave)
// == np.argmax first-max-wins. Lane 31 rebases to col 123 (argmax-neutral
// overlap). Unrolled independent iterations let the compiler pipeline loads.
__global__ __launch_bounds__(256) void k_pool(const float* __restrict__ x,
                                              const float* __restrict__ dx,
                                              bf16* __restrict__ pvb) {
  const int tid = threadIdx.x;
  const int lane = tid & 63;
  const int wid = tid >> 6;
  const int j = lane & 31;
  const int half = lane >> 5;
  const int base = (j == 31) ? 123 : 4 * j;
  const int64_t row0 = (int64_t)blockIdx.x * 128 + wid * 2 + half;
#pragma unroll
  for (int it = 0; it < 16; ++it) {
    const int64_t row = row0 + it * 8;
    const float* rp = dx + row * 127;
    float4 v = *(const float4*)(rp + base);
    float bv = fabsf(v.x);
    int bi = base;
    float a = fabsf(v.y);
    if (a > bv) { bv = a; bi = base + 1; }
    a = fabsf(v.z);
    if (a > bv) { bv = a; bi = base + 2; }
    a = fabsf(v.w);
    if (a > bv) { bv = a; bi = base + 3; }
#pragma unroll
    for (int off = 1; off < 32; off <<= 1) {
      float ov = __shfl_xor(bv, off, 64);
      int   oi = __shfl_xor(bi, off, 64);
      if (ov > bv || (ov == bv && oi < bi)) { bv = ov; bi = oi; }
    }
    if (j == 0) {
      const float* xr = x + row * L_;
      bf16x2 o;
      o[0] = (bf16)xr[bi];
      o[1] = (bf16)xr[bi + 1];
      int64_t bh = row >> 9;
      int d = (int)(row & 511);
      *(bf16x2*)(pvb + (bh << 10) + 2 * d) = o;
    }
  }
}

// ---------------- Kernel 2: transpose pvb [b][128][1024] -> XcatT[b][v][0:128] ----------------
__global__ __launch_bounds__(256) void k_tr(const bf16* __restrict__ pvb,
                                            bf16* __restrict__ XT) {
  __shared__ bf16 t[64][66];
  const int b  = blockIdx.x >> 5;
  const int hb = (blockIdx.x >> 4) & 1;
  const int vb = blockIdx.x & 15;
  const int tid = threadIdx.x;
  const bf16* src = pvb + ((int64_t)b << 17) + (int64_t)(hb << 6) * 1024 + (vb << 6);
#pragma unroll
  for (int i = 0; i < 16; ++i) {
    int e = i * 256 + tid;
    int r = e >> 6, c = e & 63;
    t[r][c] = src[(int64_t)r * 1024 + c];
  }
  __syncthreads();
  bf16* dst = XT + ((int64_t)b << 10) * 384 + (int64_t)(vb << 6) * 384 + (hb << 6);
#pragma unroll
  for (int i = 0; i < 16; ++i) {
    int e = i * 256 + tid;
    int vr = e >> 6, hc = e & 63;
    dst[(int64_t)vr * 384 + hc] = t[hc][vr];
  }
}

// ---------------- Kernel 3: adjacency via MFMA + fused softmax, writes AT bf16 ----------------
__global__ __launch_bounds__(256) void k_adj(const bf16* __restrict__ XT,
                                             bf16* __restrict__ AT) {
  const int b  = blockIdx.x >> 6;
  const int vb = blockIdx.x & 63;
  const int tid = threadIdx.x, lane = tid & 63, wid = tid >> 6;
  const int g = lane >> 4, rl = lane & 15;
  const bf16* Xb = XT + (int64_t)b * 1024 * 384;

  __shared__ bf16 lsA[16 * 128];
  __shared__ float redmax[16][4];
  __shared__ float redsum[16][4];

  {  // stage A-tile: pvT rows vb*16..+15, 128 cols, XOR-swizzled
    int row = tid >> 4, c8 = tid & 15;
    bf16x8 v = *(const bf16x8*)(Xb + (int64_t)(vb * 16 + row) * 384 + c8 * 8);
    *(bf16x8*)((char*)lsA + row * 256 + ((c8 ^ (row & 7)) << 4)) = v;
  }
  __syncthreads();

  bf16x8 af[4];
#pragma unroll
  for (int ks = 0; ks < 4; ++ks)
    af[ks] = *(const bf16x8*)((char*)lsA + rl * 256 + ((((ks << 2) | g) ^ (rl & 7)) << 4));

  f32x4 acc[16];
  f32x4 zero = {0.f, 0.f, 0.f, 0.f};
#pragma unroll
  for (int t = 0; t < 16; ++t) acc[t] = zero;

  const int nbase = wid * 256;
#pragma unroll
  for (int t = 0; t < 16; ++t) {
    const bf16* bp = Xb + (int64_t)(nbase + t * 16 + rl) * 384 + g * 8;
#pragma unroll
    for (int ks = 0; ks < 4; ++ks) {
      bf16x8 bfr = *(const bf16x8*)(bp + ks * 32);
      acc[t] = MFMA_B16(af[ks], bfr, acc[t]);
    }
  }

  const int vg0 = vb * 16 + g * 4;
  float rmax[4] = {-1e30f, -1e30f, -1e30f, -1e30f};
#pragma unroll
  for (int t = 0; t < 16; ++t) {
    int n = nbase + t * 16 + rl;
#pragma unroll
    for (int r = 0; r < 4; ++r) {
      float a = acc[t][r] * (1.0f / 1024.0f);
      if (n == vg0 + r) a -= 1e8f;
      a = (a > 0.f) ? a : 0.01f * a;
      acc[t][r] = a;
      rmax[r] = fmaxf(rmax[r], a);
    }
  }
#pragma unroll
  for (int r = 0; r < 4; ++r)
#pragma unroll
    for (int off = 1; off < 16; off <<= 1)
      rmax[r] = fmaxf(rmax[r], __shfl_xor(rmax[r], off, 64));
  if (rl == 0)
#pragma unroll
    for (int r = 0; r < 4; ++r) redmax[g * 4 + r][wid] = rmax[r];
  __syncthreads();
#pragma unroll
  for (int r = 0; r < 4; ++r)
    rmax[r] = fmaxf(fmaxf(redmax[g * 4 + r][0], redmax[g * 4 + r][1]),
                    fmaxf(redmax[g * 4 + r][2], redmax[g * 4 + r][3]));

  float rsum[4] = {0.f, 0.f, 0.f, 0.f};
#pragma unroll
  for (int t = 0; t < 16; ++t)
#pragma unroll
    for (int r = 0; r < 4; ++r) {
      float e = __expf(acc[t][r] - rmax[r]);
      acc[t][r] = e;
      rsum[r] += e;
    }
#pragma unroll
  for (int r = 0; r < 4; ++r)
#pragma unroll
    for (int off = 1; off < 16; off <<= 1) rsum[r] += __shfl_xor(rsum[r], off, 64);
  if (rl == 0)
#pragma unroll
    for (int r = 0; r < 4; ++r) redsum[g * 4 + r][wid] = rsum[r];
  __syncthreads();
#pragma unroll
  for (int r = 0; r < 4; ++r) {
    float s = redsum[g * 4 + r][0] + redsum[g * 4 + r][1] +
              redsum[g * 4 + r][2] + redsum[g * 4 + r][3];
    rsum[r] = 1.0f / s;
  }

  bf16* ATb = AT + ((int64_t)b << 20);
#pragma unroll
  for (int t = 0; t < 16; ++t) {
    int n = nbase + t * 16 + rl;
    bf16x4 o;
#pragma unroll
    for (int r = 0; r < 4; ++r) {
      float v = acc[t][r] * rsum[r] + ((n == vg0 + r) ? 1.0f : 0.0f);
      o[r] = (bf16)v;
    }
    *(bf16x4*)(ATb + (int64_t)n * 1024 + vb * 16 + g * 4) = o;
  }
}

// ---------------- Kernel 4: Y = Xa(128x1024) @ A via AT ----------------
// global_load_lds width=16 with pre-swizzled global source (rule #21): linear
// LDS dest; LDS slot row*64+c8*8 receives G[row][(c8^(row&7))*8]; fragment
// reads keep the swizzled layout.
template <int WRITE_ROW, int TCOL>
__global__ __launch_bounds__(256) void k_gemm(const bf16* __restrict__ Xa,
                                              const bf16* __restrict__ AT,
                                              bf16* __restrict__ Yrow,
                                              bf16* __restrict__ XT) {
  const int b  = blockIdx.x >> 4;
  const int n0 = (blockIdx.x & 15) << 6;
  const int tid = threadIdx.x, lane = tid & 63, wid = tid >> 6;
  const int g = lane >> 4, rl = lane & 15;
  const bf16* Xb = Xa + ((int64_t)b << 17);
  const bf16* Ab = AT + ((int64_t)b << 20);

  __shared__ bf16 lsA[128 * 64];
  __shared__ bf16 lsB[64 * 64];

  const int wbase = tid & ~63;  // wave-uniform lane-block start

  auto STAGE = [&](int ks) {
    const int k0 = ks << 6;
#pragma unroll
    for (int i = 0; i < 4; ++i) {
      int f = (i << 8) + tid;
      int row = f >> 3;
      int sc8 = (f & 7) ^ (row & 7);
      const bf16* src = Xb + (int64_t)row * 1024 + k0 + (sc8 << 3);
      char* dst = (char*)lsA + (((i << 8) + wbase) << 4);
      __builtin_amdgcn_global_load_lds(
          (const __attribute__((address_space(1))) void*)src,
          (__attribute__((address_space(3))) void*)dst, 16, 0, 0);
    }
#pragma unroll
    for (int i = 0; i < 2; ++i) {
      int f = (i << 8) + tid;
      int row = f >> 3;
      int sc8 = (f & 7) ^ (row & 7);
      const bf16* src = Ab + (int64_t)(n0 + row) * 1024 + k0 + (sc8 << 3);
      char* dst = (char*)lsB + (((i << 8) + wbase) << 4);
      __builtin_amdgcn_global_load_lds(
          (const __attribute__((address_space(1))) void*)src,
          (__attribute__((address_space(3))) void*)dst, 16, 0, 0);
    }
  };

  f32x4 acc[2][4];
  f32x4 zero = {0.f, 0.f, 0.f, 0.f};
#pragma unroll
  for (int mi = 0; mi < 2; ++mi)
#pragma unroll
    for (int ni = 0; ni < 4; ++ni) acc[mi][ni] = zero;

  STAGE(0);
  __syncthreads();

  for (int ks = 0; ks < 16; ++ks) {
    bf16x8 afr[2][2], bfr[4][2];
#pragma unroll
    for (int mi = 0; mi < 2; ++mi)
#pragma unroll
      for (int ku = 0; ku < 2; ++ku) {
        int row = wid * 32 + mi * 16 + rl;
        afr[mi][ku] = *(const bf16x8*)((char*)lsA + row * 128 +
                                       ((((ku << 2) | g) ^ (rl & 7)) << 4));
      }
#pragma unroll
    for (int ni = 0; ni < 4; ++ni)
#pragma unroll
      for (int ku = 0; ku < 2; ++ku) {
        int row = ni * 16 + rl;
        bfr[ni][ku] = *(const bf16x8*)((char*)lsB + row * 128 +
                                       ((((ku << 2) | g) ^ (rl & 7)) << 4));
      }
    __syncthreads();
    if (ks < 15) STAGE(ks + 1);
#pragma unroll
    for (int ku = 0; ku < 2; ++ku)
#pragma unroll
      for (int mi = 0; mi < 2; ++mi)
#pragma unroll
        for (int ni = 0; ni < 4; ++ni)
          acc[mi][ni] = MFMA_B16(afr[mi][ku], bfr[ni][ku], acc[mi][ni]);
    __syncthreads();
  }

#pragma unroll
  for (int mi = 0; mi < 2; ++mi)
#pragma unroll
    for (int ni = 0; ni < 4; ++ni) {
      int c0 = wid * 32 + mi * 16 + g * 4;
      int w  = n0 + ni * 16 + rl;
      if (WRITE_ROW) {
#pragma unroll
        for (int q = 0; q < 4; ++q)
          Yrow[((int64_t)b << 17) + (int64_t)(c0 + q) * 1024 + w] = (bf16)acc[mi][ni][q];
      }
      bf16x4 o;
#pragma unroll
      for (int q = 0; q < 4; ++q) o[q] = (bf16)acc[mi][ni][q];
      *(bf16x4*)(XT + ((int64_t)b * 1024 + w) * 384 + TCOL + c0) = o;
    }
}

// ---------------- Kernel 5: h = W(128x384, f32 cast on the fly) @ XcatT^T + bias ----------------
__global__ __launch_bounds__(256) void k_conv(const float* __restrict__ W,
                                              const bf16* __restrict__ XT,
                                              const float* __restrict__ bias,
                                              float* __restrict__ h) {
  const int b  = blockIdx.x >> 4;
  const int n0 = (blockIdx.x & 15) << 6;
  const int tid = threadIdx.x, lane = tid & 63, wid = tid >> 6;
  const int g = lane >> 4, rl = lane & 15;
  const bf16* Xb = XT + (int64_t)b * 1024 * 384;

  __shared__ bf16 lsA[128 * 64];
  __shared__ bf16 lsB[64 * 64];

  bf16x8 stA[4], stB[2];

  auto LOAD = [&](int ks) {
    const int k0 = ks << 6;
#pragma unroll
    for (int i = 0; i < 4; ++i) {
      int f = i * 256 + tid;
      int row = f >> 3, c8 = f & 7;
      const float* wp = W + (int64_t)row * 384 + k0 + c8 * 8;
      float4 a0 = *(const float4*)(wp);
      float4 a1 = *(const float4*)(wp + 4);
      bf16x8 r;
      r[0] = (bf16)a0.x; r[1] = (bf16)a0.y; r[2] = (bf16)a0.z; r[3] = (bf16)a0.w;
      r[4] = (bf16)a1.x; r[5] = (bf16)a1.y; r[6] = (bf16)a1.z; r[7] = (bf16)a1.w;
      stA[i] = r;
    }
#pragma unroll
    for (int i = 0; i < 2; ++i) {
      int f = i * 256 + tid;
      int row = f >> 3, c8 = f & 7;
      stB[i] = *(const bf16x8*)(Xb + (int64_t)(n0 + row) * 384 + k0 + c8 * 8);
    }
  };
  auto WRITE = [&]() {
#pragma unroll
    for (int i = 0; i < 4; ++i) {
      int f = i * 256 + tid;
      int row = f >> 3, c8 = f & 7;
      *(bf16x8*)((char*)lsA + row * 128 + ((c8 ^ (row & 7)) << 4)) = stA[i];
    }
#pragma unroll
    for (int i = 0; i < 2; ++i) {
      int f = i * 256 + tid;
      int row = f >> 3, c8 = f & 7;
      *(bf16x8*)((char*)lsB + row * 128 + ((c8 ^ (row & 7)) << 4)) = stB[i];
    }
  };

  f32x4 acc[2][4];
  f32x4 zero = {0.f, 0.f, 0.f, 0.f};
#pragma unroll
  for (int mi = 0; mi < 2; ++mi)
#pragma unroll
    for (int ni = 0; ni < 4; ++ni) acc[mi][ni] = zero;

  LOAD(0);
  WRITE();
  __syncthreads();

  for (int ks = 0; ks < 6; ++ks) {
    bf16x8 afr[2][2], bfr[4][2];
#pragma unroll
    for (int mi = 0; mi < 2; ++mi)
#pragma unroll
      for (int ku = 0; ku < 2; ++ku) {
        int row = wid * 32 + mi * 16 + rl;
        afr[mi][ku] = *(const bf16x8*)((char*)lsA + row * 128 +
                                       ((((ku << 2) | g) ^ (rl & 7)) << 4));
      }
#pragma unroll
    for (int ni = 0; ni < 4; ++ni)
#pragma unroll
      for (int ku = 0; ku < 2; ++ku) {
        int row = ni * 16 + rl;
        bfr[ni][ku] = *(const bf16x8*)((char*)lsB + row * 128 +
                                       ((((ku << 2) | g) ^ (rl & 7)) << 4));
      }
    if (ks < 5) LOAD(ks + 1);
    __syncthreads();
    if (ks < 5) WRITE();
#pragma unroll
    for (int ku = 0; ku < 2; ++ku)
#pragma unroll
      for (int mi = 0; mi < 2; ++mi)
#pragma unroll
        for (int ni = 0; ni < 4; ++ni)
          acc[mi][ni] = MFMA_B16(afr[mi][ku], bfr[ni][ku], acc[mi][ni]);
    __syncthreads();
  }

#pragma unroll
  for (int mi = 0; mi < 2; ++mi)
#pragma unroll
    for (int ni = 0; ni < 4; ++ni) {
      int c0 = wid * 32 + mi * 16 + g * 4;
      int w  = n0 + ni * 16 + rl;
#pragma unroll
      for (int q = 0; q < 4; ++q)
        h[((int64_t)(b * 128 + c0 + q) << 10) + w] = acc[mi][ni][q] + bias[c0 + q];
    }
}

// ---------------- Kernel 6: fused BN stats + apply + output permutation ----------------
__global__ __launch_bounds__(256) void k_statsout(const float* __restrict__ hpre,
                                                  const float* __restrict__ gamma,
                                                  const float* __restrict__ beta,
                                                  float* __restrict__ out) {
  const int o = blockIdx.x;
  const int tid = threadIdx.x;
  float s = 0.f, s2 = 0.f;
  for (int e = tid; e < 8192; e += 256) {
    int bb = e >> 10, v = e & 1023;
    float val = hpre[((int64_t)(bb * 128 + o) << 10) + v];
    s += val;
    s2 = fmaf(val, val, s2);
  }
#pragma unroll
  for (int off = 1; off < 64; off <<= 1) {
    s  += __shfl_xor(s, off, 64);
    s2 += __shfl_xor(s2, off, 64);
  }
  __shared__ float rs[4], rs2[4];
  __shared__ float scsh[2];
  int lane = tid & 63, wid = tid >> 6;
  if (lane == 0) { rs[wid] = s; rs2[wid] = s2; }
  __syncthreads();
  if (tid == 0) {
    float S  = rs[0] + rs[1] + rs[2] + rs[3];
    float S2 = rs2[0] + rs2[1] + rs2[2] + rs2[3];
    float mean = S * (1.0f / 8192.0f);
    float var  = S2 * (1.0f / 8192.0f) - mean * mean;
    float istd = rsqrtf(var + 1e-5f);
    float scale = gamma[o] * istd;
    scsh[0] = scale;
    scsh[1] = beta[o] - mean * scale;
  }
  __syncthreads();
  const float sc = scsh[0], sh = scsh[1];
  for (int q = tid; q < 8192; q += 256) {
    int b  = q >> 10;
    int pd = q & 1023;
    int p  = pd >> 9;
    int d  = pd & 511;
    float val = hpre[(((int64_t)(b * 128 + o)) << 10) + 2 * d + p];
    out[(((int64_t)(b * 256 + p * 128 + o)) << 9) + d] = fmaf(val, sc, sh);
  }
}

extern "C" void kernel_launch(void* const* d_in, const int* in_sizes, int n_in,
                              void* d_out, int out_size, void* d_ws, size_t ws_size,
                              hipStream_t stream) {
  const float* x     = (const float*)d_in[0];
  const float* dx    = (const float*)d_in[1];
  const float* W     = (const float*)d_in[2];
  const float* cb    = (const float*)d_in[3];
  const float* gamma = (const float*)d_in[4];
  const float* beta  = (const float*)d_in[5];

  char* ws = (char*)d_ws;
  bf16*   XcatT = (bf16*)(ws);                    //  6,291,456 B  [8][1024][384]
  bf16*   AT    = (bf16*)(ws + 6291456);          // 16,777,216 B  [8][1024][1024]
  bf16*   pvb   = (bf16*)(ws + 23068672);         //  2,097,152 B  [8][128][1024]
  bf16*   x1b   = (bf16*)(ws + 25165824);         //  2,097,152 B  [8][128][1024]
  float*  h     = (float*)(ws + 27361280);        //  4,194,304 B  [8][128][1024]
  float* out    = (float*)d_out;

  k_pool<<<4096, 256, 0, stream>>>(x, dx, pvb);
  k_tr<<<256, 256, 0, stream>>>(pvb, XcatT);
  k_adj<<<512, 256, 0, stream>>>(XcatT, AT);
  k_gemm<1, 128><<<128, 256, 0, stream>>>(pvb, AT, x1b, XcatT);
  k_gemm<0, 256><<<128, 256, 0, stream>>>(x1b, AT, nullptr, XcatT);
  k_conv<<<128, 256, 0, stream>>>(W, XcatT, cb, h);
  k_statsout<<<128, 256, 0, stream>>>(h, gamma, beta, out);
}

// Round 12
// 144.029 us; speedup vs baseline: 1.1062x; 1.1062x over previous
//
#include <hip/hip_runtime.h>
#include <cstdint>

// Dims: B=8, H=128, D=512, L=128, V=2D=1024, inner=384
#define L_ 128

using bf16   = __bf16;
using bf16x2 = __attribute__((ext_vector_type(2))) __bf16;
using bf16x4 = __attribute__((ext_vector_type(4))) __bf16;
using bf16x8 = __attribute__((ext_vector_type(8))) __bf16;
using f32x4  = __attribute__((ext_vector_type(4))) float;

#define MFMA_B16(a, b, c) __builtin_amdgcn_mfma_f32_16x16x32_bf16((a), (b), (c), 0, 0, 0)

// ---------------- Kernel 1: argmax(|d_x|) + gather -> pv bf16 [B,H,V] ----------------
// Best measured variant (R6/R10): 4 lanes/row, 8 x float4 per lane; ascending
// strict-> scan + (val,idx) lexicographic quad butterfly == np.argmax
// first-max-wins semantics.
__global__ __launch_bounds__(256) void k_pool(const float* __restrict__ x,
                                              const float* __restrict__ dx,
                                              bf16* __restrict__ pvb) {
  const int64_t gt = (int64_t)blockIdx.x * 256 + threadIdx.x;
  const int64_t row = gt >> 2;
  const int j = (int)(gt & 3);
  const float* rp = dx + row * 127;

  float bv = -1.0f;
  int bi = 0;
#pragma unroll
  for (int i = 0; i < 8; ++i) {
    int base = 16 * i + 4 * j;
    if (base > 123) base = 123;  // only j==3,i==7
    float4 v = *(const float4*)(rp + base);
    float a = fabsf(v.x);
    if (a > bv) { bv = a; bi = base; }
    a = fabsf(v.y);
    if (a > bv) { bv = a; bi = base + 1; }
    a = fabsf(v.z);
    if (a > bv) { bv = a; bi = base + 2; }
    a = fabsf(v.w);
    if (a > bv) { bv = a; bi = base + 3; }
  }
#pragma unroll
  for (int off = 1; off <= 2; off <<= 1) {
    float ov = __shfl_xor(bv, off, 64);
    int   oi = __shfl_xor(bi, off, 64);
    if (ov > bv || (ov == bv && oi < bi)) { bv = ov; bi = oi; }
  }
  if (j == 0) {
    const float* xr = x + row * L_;
    bf16x2 o;
    o[0] = (bf16)xr[bi];
    o[1] = (bf16)xr[bi + 1];
    int64_t bh = row >> 9;
    int d = (int)(row & 511);
    *(bf16x2*)(pvb + (bh << 10) + 2 * d) = o;
  }
}

// ---------------- Kernel 2: transpose pvb [b][128][1024] -> XcatT[b][v][0:128] ----------------
__global__ __launch_bounds__(256) void k_tr(const bf16* __restrict__ pvb,
                                            bf16* __restrict__ XT) {
  __shared__ bf16 t[64][66];
  const int b  = blockIdx.x >> 5;
  const int hb = (blockIdx.x >> 4) & 1;
  const int vb = blockIdx.x & 15;
  const int tid = threadIdx.x;
  const bf16* src = pvb + ((int64_t)b << 17) + (int64_t)(hb << 6) * 1024 + (vb << 6);
#pragma unroll
  for (int i = 0; i < 16; ++i) {
    int e = i * 256 + tid;
    int r = e >> 6, c = e & 63;
    t[r][c] = src[(int64_t)r * 1024 + c];
  }
  __syncthreads();
  bf16* dst = XT + ((int64_t)b << 10) * 384 + (int64_t)(vb << 6) * 384 + (hb << 6);
#pragma unroll
  for (int i = 0; i < 16; ++i) {
    int e = i * 256 + tid;
    int vr = e >> 6, hc = e & 63;
    dst[(int64_t)vr * 384 + hc] = t[hc][vr];
  }
}

// ---------------- Kernel 3: adjacency via MFMA + fused softmax, writes AT bf16 ----------------
__global__ __launch_bounds__(256) void k_adj(const bf16* __restrict__ XT,
                                             bf16* __restrict__ AT) {
  const int b  = blockIdx.x >> 6;
  const int vb = blockIdx.x & 63;
  const int tid = threadIdx.x, lane = tid & 63, wid = tid >> 6;
  const int g = lane >> 4, rl = lane & 15;
  const bf16* Xb = XT + (int64_t)b * 1024 * 384;

  __shared__ bf16 lsA[16 * 128];
  __shared__ float redmax[16][4];
  __shared__ float redsum[16][4];

  {  // stage A-tile: pvT rows vb*16..+15, 128 cols, XOR-swizzled
    int row = tid >> 4, c8 = tid & 15;
    bf16x8 v = *(const bf16x8*)(Xb + (int64_t)(vb * 16 + row) * 384 + c8 * 8);
    *(bf16x8*)((char*)lsA + row * 256 + ((c8 ^ (row & 7)) << 4)) = v;
  }
  __syncthreads();

  bf16x8 af[4];
#pragma unroll
  for (int ks = 0; ks < 4; ++ks)
    af[ks] = *(const bf16x8*)((char*)lsA + rl * 256 + ((((ks << 2) | g) ^ (rl & 7)) << 4));

  f32x4 acc[16];
  f32x4 zero = {0.f, 0.f, 0.f, 0.f};
#pragma unroll
  for (int t = 0; t < 16; ++t) acc[t] = zero;

  const int nbase = wid * 256;
#pragma unroll
  for (int t = 0; t < 16; ++t) {
    const bf16* bp = Xb + (int64_t)(nbase + t * 16 + rl) * 384 + g * 8;
#pragma unroll
    for (int ks = 0; ks < 4; ++ks) {
      bf16x8 bfr = *(const bf16x8*)(bp + ks * 32);
      acc[t] = MFMA_B16(af[ks], bfr, acc[t]);
    }
  }

  const int vg0 = vb * 16 + g * 4;
  float rmax[4] = {-1e30f, -1e30f, -1e30f, -1e30f};
#pragma unroll
  for (int t = 0; t < 16; ++t) {
    int n = nbase + t * 16 + rl;
#pragma unroll
    for (int r = 0; r < 4; ++r) {
      float a = acc[t][r] * (1.0f / 1024.0f);
      if (n == vg0 + r) a -= 1e8f;
      a = (a > 0.f) ? a : 0.01f * a;
      acc[t][r] = a;
      rmax[r] = fmaxf(rmax[r], a);
    }
  }
#pragma unroll
  for (int r = 0; r < 4; ++r)
#pragma unroll
    for (int off = 1; off < 16; off <<= 1)
      rmax[r] = fmaxf(rmax[r], __shfl_xor(rmax[r], off, 64));
  if (rl == 0)
#pragma unroll
    for (int r = 0; r < 4; ++r) redmax[g * 4 + r][wid] = rmax[r];
  __syncthreads();
#pragma unroll
  for (int r = 0; r < 4; ++r)
    rmax[r] = fmaxf(fmaxf(redmax[g * 4 + r][0], redmax[g * 4 + r][1]),
                    fmaxf(redmax[g * 4 + r][2], redmax[g * 4 + r][3]));

  float rsum[4] = {0.f, 0.f, 0.f, 0.f};
#pragma unroll
  for (int t = 0; t < 16; ++t)
#pragma unroll
    for (int r = 0; r < 4; ++r) {
      float e = __expf(acc[t][r] - rmax[r]);
      acc[t][r] = e;
      rsum[r] += e;
    }
#pragma unroll
  for (int r = 0; r < 4; ++r)
#pragma unroll
    for (int off = 1; off < 16; off <<= 1) rsum[r] += __shfl_xor(rsum[r], off, 64);
  if (rl == 0)
#pragma unroll
    for (int r = 0; r < 4; ++r) redsum[g * 4 + r][wid] = rsum[r];
  __syncthreads();
#pragma unroll
  for (int r = 0; r < 4; ++r) {
    float s = redsum[g * 4 + r][0] + redsum[g * 4 + r][1] +
              redsum[g * 4 + r][2] + redsum[g * 4 + r][3];
    rsum[r] = 1.0f / s;
  }

  bf16* ATb = AT + ((int64_t)b << 20);
#pragma unroll
  for (int t = 0; t < 16; ++t) {
    int n = nbase + t * 16 + rl;
    bf16x4 o;
#pragma unroll
    for (int r = 0; r < 4; ++r) {
      float v = acc[t][r] * rsum[r] + ((n == vg0 + r) ? 1.0f : 0.0f);
      o[r] = (bf16)v;
    }
    *(bf16x4*)(ATb + (int64_t)n * 1024 + vb * 16 + g * 4) = o;
  }
}

// ---------------- Kernel 4: Y = Xa(128x1024) @ A via AT ----------------
// global_load_lds width=16 with pre-swizzled global source (rule #21), now
// DOUBLE-BUFFERED with ONE barrier per K-step: STAGE(ks+1 -> buf^1) issues
// first, frag-read+MFMA consume buf, the single barrier drains the DMA
// (compiler vmcnt(0)) and proves buf is no longer read before overwrite.
template <int WRITE_ROW, int TCOL>
__global__ __launch_bounds__(256) void k_gemm(const bf16* __restrict__ Xa,
                                              const bf16* __restrict__ AT,
                                              bf16* __restrict__ Yrow,
                                              bf16* __restrict__ XT) {
  const int b  = blockIdx.x >> 4;
  const int n0 = (blockIdx.x & 15) << 6;
  const int tid = threadIdx.x, lane = tid & 63, wid = tid >> 6;
  const int g = lane >> 4, rl = lane & 15;
  const bf16* Xb = Xa + ((int64_t)b << 17);
  const bf16* Ab = AT + ((int64_t)b << 20);

  __shared__ bf16 lsA[2][128 * 64];
  __shared__ bf16 lsB[2][64 * 64];

  const int wbase = tid & ~63;  // wave-uniform lane-block start

  auto STAGE = [&](int ks, int buf) {
    const int k0 = ks << 6;
#pragma unroll
    for (int i = 0; i < 4; ++i) {
      int f = (i << 8) + tid;
      int row = f >> 3;
      int sc8 = (f & 7) ^ (row & 7);
      const bf16* src = Xb + (int64_t)row * 1024 + k0 + (sc8 << 3);
      char* dst = (char*)lsA[buf] + (((i << 8) + wbase) << 4);
      __builtin_amdgcn_global_load_lds(
          (const __attribute__((address_space(1))) void*)src,
          (__attribute__((address_space(3))) void*)dst, 16, 0, 0);
    }
#pragma unroll
    for (int i = 0; i < 2; ++i) {
      int f = (i << 8) + tid;
      int row = f >> 3;
      int sc8 = (f & 7) ^ (row & 7);
      const bf16* src = Ab + (int64_t)(n0 + row) * 1024 + k0 + (sc8 << 3);
      char* dst = (char*)lsB[buf] + (((i << 8) + wbase) << 4);
      __builtin_amdgcn_global_load_lds(
          (const __attribute__((address_space(1))) void*)src,
          (__attribute__((address_space(3))) void*)dst, 16, 0, 0);
    }
  };

  f32x4 acc[2][4];
  f32x4 zero = {0.f, 0.f, 0.f, 0.f};
#pragma unroll
  for (int mi = 0; mi < 2; ++mi)
#pragma unroll
    for (int ni = 0; ni < 4; ++ni) acc[mi][ni] = zero;

  STAGE(0, 0);
  __syncthreads();

  int cur = 0;
  for (int ks = 0; ks < 16; ++ks) {
    if (ks < 15) STAGE(ks + 1, cur ^ 1);
    bf16x8 afr[2][2], bfr[4][2];
#pragma unroll
    for (int mi = 0; mi < 2; ++mi)
#pragma unroll
      for (int ku = 0; ku < 2; ++ku) {
        int row = wid * 32 + mi * 16 + rl;
        afr[mi][ku] = *(const bf16x8*)((char*)lsA[cur] + row * 128 +
                                       ((((ku << 2) | g) ^ (rl & 7)) << 4));
      }
#pragma unroll
    for (int ni = 0; ni < 4; ++ni)
#pragma unroll
      for (int ku = 0; ku < 2; ++ku) {
        int row = ni * 16 + rl;
        bfr[ni][ku] = *(const bf16x8*)((char*)lsB[cur] + row * 128 +
                                       ((((ku << 2) | g) ^ (rl & 7)) << 4));
      }
#pragma unroll
    for (int ku = 0; ku < 2; ++ku)
#pragma unroll
      for (int mi = 0; mi < 2; ++mi)
#pragma unroll
        for (int ni = 0; ni < 4; ++ni)
          acc[mi][ni] = MFMA_B16(afr[mi][ku], bfr[ni][ku], acc[mi][ni]);
    __syncthreads();
    cur ^= 1;
  }

#pragma unroll
  for (int mi = 0; mi < 2; ++mi)
#pragma unroll
    for (int ni = 0; ni < 4; ++ni) {
      int c0 = wid * 32 + mi * 16 + g * 4;
      int w  = n0 + ni * 16 + rl;
      if (WRITE_ROW) {
#pragma unroll
        for (int q = 0; q < 4; ++q)
          Yrow[((int64_t)b << 17) + (int64_t)(c0 + q) * 1024 + w] = (bf16)acc[mi][ni][q];
      }
      bf16x4 o;
#pragma unroll
      for (int q = 0; q < 4; ++q) o[q] = (bf16)acc[mi][ni][q];
      *(bf16x4*)(XT + ((int64_t)b * 1024 + w) * 384 + TCOL + c0) = o;
    }
}

// ---------------- Kernel 5: h = W(128x384, f32 cast on the fly) @ XcatT^T + bias ----------------
// Same single-barrier double-buffer transform (reg-staged: LOAD+WRITE into
// buf^1 before the barrier; frag-read+MFMA consume buf).
__global__ __launch_bounds__(256) void k_conv(const float* __restrict__ W,
                                              const bf16* __restrict__ XT,
                                              const float* __restrict__ bias,
                                              float* __restrict__ h) {
  const int b  = blockIdx.x >> 4;
  const int n0 = (blockIdx.x & 15) << 6;
  const int tid = threadIdx.x, lane = tid & 63, wid = tid >> 6;
  const int g = lane >> 4, rl = lane & 15;
  const bf16* Xb = XT + (int64_t)b * 1024 * 384;

  __shared__ bf16 lsA[2][128 * 64];
  __shared__ bf16 lsB[2][64 * 64];

  auto LOADWRITE = [&](int ks, int buf) {
    const int k0 = ks << 6;
#pragma unroll
    for (int i = 0; i < 4; ++i) {
      int f = i * 256 + tid;
      int row = f >> 3, c8 = f & 7;
      const float* wp = W + (int64_t)row * 384 + k0 + c8 * 8;
      float4 a0 = *(const float4*)(wp);
      float4 a1 = *(const float4*)(wp + 4);
      bf16x8 r;
      r[0] = (bf16)a0.x; r[1] = (bf16)a0.y; r[2] = (bf16)a0.z; r[3] = (bf16)a0.w;
      r[4] = (bf16)a1.x; r[5] = (bf16)a1.y; r[6] = (bf16)a1.z; r[7] = (bf16)a1.w;
      *(bf16x8*)((char*)lsA[buf] + row * 128 + ((c8 ^ (row & 7)) << 4)) = r;
    }
#pragma unroll
    for (int i = 0; i < 2; ++i) {
      int f = i * 256 + tid;
      int row = f >> 3, c8 = f & 7;
      bf16x8 v = *(const bf16x8*)(Xb + (int64_t)(n0 + row) * 384 + k0 + c8 * 8);
      *(bf16x8*)((char*)lsB[buf] + row * 128 + ((c8 ^ (row & 7)) << 4)) = v;
    }
  };

  f32x4 acc[2][4];
  f32x4 zero = {0.f, 0.f, 0.f, 0.f};
#pragma unroll
  for (int mi = 0; mi < 2; ++mi)
#pragma unroll
    for (int ni = 0; ni < 4; ++ni) acc[mi][ni] = zero;

  LOADWRITE(0, 0);
  __syncthreads();

  int cur = 0;
  for (int ks = 0; ks < 6; ++ks) {
    if (ks < 5) LOADWRITE(ks + 1, cur ^ 1);
    bf16x8 afr[2][2], bfr[4][2];
#pragma unroll
    for (int mi = 0; mi < 2; ++mi)
#pragma unroll
      for (int ku = 0; ku < 2; ++ku) {
        int row = wid * 32 + mi * 16 + rl;
        afr[mi][ku] = *(const bf16x8*)((char*)lsA[cur] + row * 128 +
                                       ((((ku << 2) | g) ^ (rl & 7)) << 4));
      }
#pragma unroll
    for (int ni = 0; ni < 4; ++ni)
#pragma unroll
      for (int ku = 0; ku < 2; ++ku) {
        int row = ni * 16 + rl;
        bfr[ni][ku] = *(const bf16x8*)((char*)lsB[cur] + row * 128 +
                                       ((((ku << 2) | g) ^ (rl & 7)) << 4));
      }
#pragma unroll
    for (int ku = 0; ku < 2; ++ku)
#pragma unroll
      for (int mi = 0; mi < 2; ++mi)
#pragma unroll
        for (int ni = 0; ni < 4; ++ni)
          acc[mi][ni] = MFMA_B16(afr[mi][ku], bfr[ni][ku], acc[mi][ni]);
    __syncthreads();
    cur ^= 1;
  }

#pragma unroll
  for (int mi = 0; mi < 2; ++mi)
#pragma unroll
    for (int ni = 0; ni < 4; ++ni) {
      int c0 = wid * 32 + mi * 16 + g * 4;
      int w  = n0 + ni * 16 + rl;
#pragma unroll
      for (int q = 0; q < 4; ++q)
        h[((int64_t)(b * 128 + c0 + q) << 10) + w] = acc[mi][ni][q] + bias[c0 + q];
    }
}

// ---------------- Kernel 6: fused BN stats + apply + output permutation ----------------
__global__ __launch_bounds__(256) void k_statsout(const float* __restrict__ hpre,
                                                  const float* __restrict__ gamma,
                                                  const float* __restrict__ beta,
                                                  float* __restrict__ out) {
  const int o = blockIdx.x;
  const int tid = threadIdx.x;
  float s = 0.f, s2 = 0.f;
  for (int e = tid; e < 8192; e += 256) {
    int bb = e >> 10, v = e & 1023;
    float val = hpre[((int64_t)(bb * 128 + o) << 10) + v];
    s += val;
    s2 = fmaf(val, val, s2);
  }
#pragma unroll
  for (int off = 1; off < 64; off <<= 1) {
    s  += __shfl_xor(s, off, 64);
    s2 += __shfl_xor(s2, off, 64);
  }
  __shared__ float rs[4], rs2[4];
  __shared__ float scsh[2];
  int lane = tid & 63, wid = tid >> 6;
  if (lane == 0) { rs[wid] = s; rs2[wid] = s2; }
  __syncthreads();
  if (tid == 0) {
    float S  = rs[0] + rs[1] + rs[2] + rs[3];
    float S2 = rs2[0] + rs2[1] + rs2[2] + rs2[3];
    float mean = S * (1.0f / 8192.0f);
    float var  = S2 * (1.0f / 8192.0f) - mean * mean;
    float istd = rsqrtf(var + 1e-5f);
    float scale = gamma[o] * istd;
    scsh[0] = scale;
    scsh[1] = beta[o] - mean * scale;
  }
  __syncthreads();
  const float sc = scsh[0], sh = scsh[1];
  for (int q = tid; q < 8192; q += 256) {
    int b  = q >> 10;
    int pd = q & 1023;
    int p  = pd >> 9;
    int d  = pd & 511;
    float val = hpre[(((int64_t)(b * 128 + o)) << 10) + 2 * d + p];
    out[(((int64_t)(b * 256 + p * 128 + o)) << 9) + d] = fmaf(val, sc, sh);
  }
}

extern "C" void kernel_launch(void* const* d_in, const int* in_sizes, int n_in,
                              void* d_out, int out_size, void* d_ws, size_t ws_size,
                              hipStream_t stream) {
  const float* x     = (const float*)d_in[0];
  const float* dx    = (const float*)d_in[1];
  const float* W     = (const float*)d_in[2];
  const float* cb    = (const float*)d_in[3];
  const float* gamma = (const float*)d_in[4];
  const float* beta  = (const float*)d_in[5];

  char* ws = (char*)d_ws;
  bf16*   XcatT = (bf16*)(ws);                    //  6,291,456 B  [8][1024][384]
  bf16*   AT    = (bf16*)(ws + 6291456);          // 16,777,216 B  [8][1024][1024]
  bf16*   pvb   = (bf16*)(ws + 23068672);         //  2,097,152 B  [8][128][1024]
  bf16*   x1b   = (bf16*)(ws + 25165824);         //  2,097,152 B  [8][128][1024]
  float*  h     = (float*)(ws + 27361280);        //  4,194,304 B  [8][128][1024]
  float* out    = (float*)d_out;

  k_pool<<<8192, 256, 0, stream>>>(x, dx, pvb);
  k_tr<<<256, 256, 0, stream>>>(pvb, XcatT);
  k_adj<<<512, 256, 0, stream>>>(XcatT, AT);
  k_gemm<1, 128><<<128, 256, 0, stream>>>(pvb, AT, x1b, XcatT);
  k_gemm<0, 256><<<128, 256, 0, stream>>>(x1b, AT, nullptr, XcatT);
  k_conv<<<128, 256, 0, stream>>>(W, XcatT, cb, h);
  k_statsout<<<128, 256, 0, stream>>>(h, gamma, beta, out);
}

// Round 13
// 140.719 us; speedup vs baseline: 1.1323x; 1.0235x over previous
//
#include <hip/hip_runtime.h>
#include <cstdint>

// Dims: B=8, H=128, D=512, L=128, V=2D=1024, inner=384
#define L_ 128

using bf16   = __bf16;
using bf16x2 = __attribute__((ext_vector_type(2))) __bf16;
using bf16x4 = __attribute__((ext_vector_type(4))) __bf16;
using bf16x8 = __attribute__((ext_vector_type(8))) __bf16;
using f32x4  = __attribute__((ext_vector_type(4))) float;

#define MFMA_B16(a, b, c) __builtin_amdgcn_mfma_f32_16x16x32_bf16((a), (b), (c), 0, 0, 0)

// ---------------- Kernel 1: argmax(|d_x|) + gather -> pv bf16 [B,H,V] ----------------
// Best measured variant (R6/R10): 4 lanes/row, 8 x float4 per lane; ascending
// strict-> scan + (val,idx) lexicographic quad butterfly == np.argmax
// first-max-wins semantics.
__global__ __launch_bounds__(256) void k_pool(const float* __restrict__ x,
                                              const float* __restrict__ dx,
                                              bf16* __restrict__ pvb) {
  const int64_t gt = (int64_t)blockIdx.x * 256 + threadIdx.x;
  const int64_t row = gt >> 2;
  const int j = (int)(gt & 3);
  const float* rp = dx + row * 127;

  float bv = -1.0f;
  int bi = 0;
#pragma unroll
  for (int i = 0; i < 8; ++i) {
    int base = 16 * i + 4 * j;
    if (base > 123) base = 123;  // only j==3,i==7
    float4 v = *(const float4*)(rp + base);
    float a = fabsf(v.x);
    if (a > bv) { bv = a; bi = base; }
    a = fabsf(v.y);
    if (a > bv) { bv = a; bi = base + 1; }
    a = fabsf(v.z);
    if (a > bv) { bv = a; bi = base + 2; }
    a = fabsf(v.w);
    if (a > bv) { bv = a; bi = base + 3; }
  }
#pragma unroll
  for (int off = 1; off <= 2; off <<= 1) {
    float ov = __shfl_xor(bv, off, 64);
    int   oi = __shfl_xor(bi, off, 64);
    if (ov > bv || (ov == bv && oi < bi)) { bv = ov; bi = oi; }
  }
  if (j == 0) {
    const float* xr = x + row * L_;
    bf16x2 o;
    o[0] = (bf16)xr[bi];
    o[1] = (bf16)xr[bi + 1];
    int64_t bh = row >> 9;
    int d = (int)(row & 511);
    *(bf16x2*)(pvb + (bh << 10) + 2 * d) = o;
  }
}

// ---------------- Kernel 2: transpose pvb [b][128][1024] -> XcatT[b][v][0:128] ----------------
__global__ __launch_bounds__(256) void k_tr(const bf16* __restrict__ pvb,
                                            bf16* __restrict__ XT) {
  __shared__ bf16 t[64][66];
  const int b  = blockIdx.x >> 5;
  const int hb = (blockIdx.x >> 4) & 1;
  const int vb = blockIdx.x & 15;
  const int tid = threadIdx.x;
  const bf16* src = pvb + ((int64_t)b << 17) + (int64_t)(hb << 6) * 1024 + (vb << 6);
#pragma unroll
  for (int i = 0; i < 16; ++i) {
    int e = i * 256 + tid;
    int r = e >> 6, c = e & 63;
    t[r][c] = src[(int64_t)r * 1024 + c];
  }
  __syncthreads();
  bf16* dst = XT + ((int64_t)b << 10) * 384 + (int64_t)(vb << 6) * 384 + (hb << 6);
#pragma unroll
  for (int i = 0; i < 16; ++i) {
    int e = i * 256 + tid;
    int vr = e >> 6, hc = e & 63;
    dst[(int64_t)vr * 384 + hc] = t[hc][vr];
  }
}

// ---------------- Kernel 3: adjacency via MFMA + fused softmax, writes AT bf16 ----------------
__global__ __launch_bounds__(256) void k_adj(const bf16* __restrict__ XT,
                                             bf16* __restrict__ AT) {
  const int b  = blockIdx.x >> 6;
  const int vb = blockIdx.x & 63;
  const int tid = threadIdx.x, lane = tid & 63, wid = tid >> 6;
  const int g = lane >> 4, rl = lane & 15;
  const bf16* Xb = XT + (int64_t)b * 1024 * 384;

  __shared__ bf16 lsA[16 * 128];
  __shared__ float redmax[16][4];
  __shared__ float redsum[16][4];

  {  // stage A-tile: pvT rows vb*16..+15, 128 cols, XOR-swizzled
    int row = tid >> 4, c8 = tid & 15;
    bf16x8 v = *(const bf16x8*)(Xb + (int64_t)(vb * 16 + row) * 384 + c8 * 8);
    *(bf16x8*)((char*)lsA + row * 256 + ((c8 ^ (row & 7)) << 4)) = v;
  }
  __syncthreads();

  bf16x8 af[4];
#pragma unroll
  for (int ks = 0; ks < 4; ++ks)
    af[ks] = *(const bf16x8*)((char*)lsA + rl * 256 + ((((ks << 2) | g) ^ (rl & 7)) << 4));

  f32x4 acc[16];
  f32x4 zero = {0.f, 0.f, 0.f, 0.f};
#pragma unroll
  for (int t = 0; t < 16; ++t) acc[t] = zero;

  const int nbase = wid * 256;
#pragma unroll
  for (int t = 0; t < 16; ++t) {
    const bf16* bp = Xb + (int64_t)(nbase + t * 16 + rl) * 384 + g * 8;
#pragma unroll
    for (int ks = 0; ks < 4; ++ks) {
      bf16x8 bfr = *(const bf16x8*)(bp + ks * 32);
      acc[t] = MFMA_B16(af[ks], bfr, acc[t]);
    }
  }

  const int vg0 = vb * 16 + g * 4;
  float rmax[4] = {-1e30f, -1e30f, -1e30f, -1e30f};
#pragma unroll
  for (int t = 0; t < 16; ++t) {
    int n = nbase + t * 16 + rl;
#pragma unroll
    for (int r = 0; r < 4; ++r) {
      float a = acc[t][r] * (1.0f / 1024.0f);
      if (n == vg0 + r) a -= 1e8f;
      a = (a > 0.f) ? a : 0.01f * a;
      acc[t][r] = a;
      rmax[r] = fmaxf(rmax[r], a);
    }
  }
#pragma unroll
  for (int r = 0; r < 4; ++r)
#pragma unroll
    for (int off = 1; off < 16; off <<= 1)
      rmax[r] = fmaxf(rmax[r], __shfl_xor(rmax[r], off, 64));
  if (rl == 0)
#pragma unroll
    for (int r = 0; r < 4; ++r) redmax[g * 4 + r][wid] = rmax[r];
  __syncthreads();
#pragma unroll
  for (int r = 0; r < 4; ++r)
    rmax[r] = fmaxf(fmaxf(redmax[g * 4 + r][0], redmax[g * 4 + r][1]),
                    fmaxf(redmax[g * 4 + r][2], redmax[g * 4 + r][3]));

  float rsum[4] = {0.f, 0.f, 0.f, 0.f};
#pragma unroll
  for (int t = 0; t < 16; ++t)
#pragma unroll
    for (int r = 0; r < 4; ++r) {
      float e = __expf(acc[t][r] - rmax[r]);
      acc[t][r] = e;
      rsum[r] += e;
    }
#pragma unroll
  for (int r = 0; r < 4; ++r)
#pragma unroll
    for (int off = 1; off < 16; off <<= 1) rsum[r] += __shfl_xor(rsum[r], off, 64);
  if (rl == 0)
#pragma unroll
    for (int r = 0; r < 4; ++r) redsum[g * 4 + r][wid] = rsum[r];
  __syncthreads();
#pragma unroll
  for (int r = 0; r < 4; ++r) {
    float s = redsum[g * 4 + r][0] + redsum[g * 4 + r][1] +
              redsum[g * 4 + r][2] + redsum[g * 4 + r][3];
    rsum[r] = 1.0f / s;
  }

  bf16* ATb = AT + ((int64_t)b << 20);
#pragma unroll
  for (int t = 0; t < 16; ++t) {
    int n = nbase + t * 16 + rl;
    bf16x4 o;
#pragma unroll
    for (int r = 0; r < 4; ++r) {
      float v = acc[t][r] * rsum[r] + ((n == vg0 + r) ? 1.0f : 0.0f);
      o[r] = (bf16)v;
    }
    *(bf16x4*)(ATb + (int64_t)n * 1024 + vb * 16 + g * 4) = o;
  }
}

// ---------------- Kernel 4: Y = Xa(128x1024) @ A via AT ----------------
// global_load_lds width=16 with pre-swizzled global source (rule #21): linear
// LDS dest; LDS slot row*64+c8*8 receives G[row][(c8^(row&7))*8]; fragment
// reads keep the swizzled layout.
template <int WRITE_ROW, int TCOL>
__global__ __launch_bounds__(256) void k_gemm(const bf16* __restrict__ Xa,
                                              const bf16* __restrict__ AT,
                                              bf16* __restrict__ Yrow,
                                              bf16* __restrict__ XT) {
  const int b  = blockIdx.x >> 4;
  const int n0 = (blockIdx.x & 15) << 6;
  const int tid = threadIdx.x, lane = tid & 63, wid = tid >> 6;
  const int g = lane >> 4, rl = lane & 15;
  const bf16* Xb = Xa + ((int64_t)b << 17);
  const bf16* Ab = AT + ((int64_t)b << 20);

  __shared__ bf16 lsA[128 * 64];
  __shared__ bf16 lsB[64 * 64];

  const int wbase = tid & ~63;  // wave-uniform lane-block start

  auto STAGE = [&](int ks) {
    const int k0 = ks << 6;
#pragma unroll
    for (int i = 0; i < 4; ++i) {
      int f = (i << 8) + tid;
      int row = f >> 3;
      int sc8 = (f & 7) ^ (row & 7);
      const bf16* src = Xb + (int64_t)row * 1024 + k0 + (sc8 << 3);
      char* dst = (char*)lsA + (((i << 8) + wbase) << 4);
      __builtin_amdgcn_global_load_lds(
          (const __attribute__((address_space(1))) void*)src,
          (__attribute__((address_space(3))) void*)dst, 16, 0, 0);
    }
#pragma unroll
    for (int i = 0; i < 2; ++i) {
      int f = (i << 8) + tid;
      int row = f >> 3;
      int sc8 = (f & 7) ^ (row & 7);
      const bf16* src = Ab + (int64_t)(n0 + row) * 1024 + k0 + (sc8 << 3);
      char* dst = (char*)lsB + (((i << 8) + wbase) << 4);
      __builtin_amdgcn_global_load_lds(
          (const __attribute__((address_space(1))) void*)src,
          (__attribute__((address_space(3))) void*)dst, 16, 0, 0);
    }
  };

  f32x4 acc[2][4];
  f32x4 zero = {0.f, 0.f, 0.f, 0.f};
#pragma unroll
  for (int mi = 0; mi < 2; ++mi)
#pragma unroll
    for (int ni = 0; ni < 4; ++ni) acc[mi][ni] = zero;

  STAGE(0);
  __syncthreads();

  for (int ks = 0; ks < 16; ++ks) {
    bf16x8 afr[2][2], bfr[4][2];
#pragma unroll
    for (int mi = 0; mi < 2; ++mi)
#pragma unroll
      for (int ku = 0; ku < 2; ++ku) {
        int row = wid * 32 + mi * 16 + rl;
        afr[mi][ku] = *(const bf16x8*)((char*)lsA + row * 128 +
                                       ((((ku << 2) | g) ^ (rl & 7)) << 4));
      }
#pragma unroll
    for (int ni = 0; ni < 4; ++ni)
#pragma unroll
      for (int ku = 0; ku < 2; ++ku) {
        int row = ni * 16 + rl;
        bfr[ni][ku] = *(const bf16x8*)((char*)lsB + row * 128 +
                                       ((((ku << 2) | g) ^ (rl & 7)) << 4));
      }
    __syncthreads();
    if (ks < 15) STAGE(ks + 1);
#pragma unroll
    for (int ku = 0; ku < 2; ++ku)
#pragma unroll
      for (int mi = 0; mi < 2; ++mi)
#pragma unroll
        for (int ni = 0; ni < 4; ++ni)
          acc[mi][ni] = MFMA_B16(afr[mi][ku], bfr[ni][ku], acc[mi][ni]);
    __syncthreads();
  }

#pragma unroll
  for (int mi = 0; mi < 2; ++mi)
#pragma unroll
    for (int ni = 0; ni < 4; ++ni) {
      int c0 = wid * 32 + mi * 16 + g * 4;
      int w  = n0 + ni * 16 + rl;
      if (WRITE_ROW) {
#pragma unroll
        for (int q = 0; q < 4; ++q)
          Yrow[((int64_t)b << 17) + (int64_t)(c0 + q) * 1024 + w] = (bf16)acc[mi][ni][q];
      }
      bf16x4 o;
#pragma unroll
      for (int q = 0; q < 4; ++q) o[q] = (bf16)acc[mi][ni][q];
      *(bf16x4*)(XT + ((int64_t)b * 1024 + w) * 384 + TCOL + c0) = o;
    }
}

// ---------------- Kernel 5: h = W(128x384, f32 cast on the fly) @ XcatT^T + bias ----------------
__global__ __launch_bounds__(256) void k_conv(const float* __restrict__ W,
                                              const bf16* __restrict__ XT,
                                              const float* __restrict__ bias,
                                              float* __restrict__ h) {
  const int b  = blockIdx.x >> 4;
  const int n0 = (blockIdx.x & 15) << 6;
  const int tid = threadIdx.x, lane = tid & 63, wid = tid >> 6;
  const int g = lane >> 4, rl = lane & 15;
  const bf16* Xb = XT + (int64_t)b * 1024 * 384;

  __shared__ bf16 lsA[128 * 64];
  __shared__ bf16 lsB[64 * 64];

  bf16x8 stA[4], stB[2];

  auto LOAD = [&](int ks) {
    const int k0 = ks << 6;
#pragma unroll
    for (int i = 0; i < 4; ++i) {
      int f = i * 256 + tid;
      int row = f >> 3, c8 = f & 7;
      const float* wp = W + (int64_t)row * 384 + k0 + c8 * 8;
      float4 a0 = *(const float4*)(wp);
      float4 a1 = *(const float4*)(wp + 4);
      bf16x8 r;
      r[0] = (bf16)a0.x; r[1] = (bf16)a0.y; r[2] = (bf16)a0.z; r[3] = (bf16)a0.w;
      r[4] = (bf16)a1.x; r[5] = (bf16)a1.y; r[6] = (bf16)a1.z; r[7] = (bf16)a1.w;
      stA[i] = r;
    }
#pragma unroll
    for (int i = 0; i < 2; ++i) {
      int f = i * 256 + tid;
      int row = f >> 3, c8 = f & 7;
      stB[i] = *(const bf16x8*)(Xb + (int64_t)(n0 + row) * 384 + k0 + c8 * 8);
    }
  };
  auto WRITE = [&]() {
#pragma unroll
    for (int i = 0; i < 4; ++i) {
      int f = i * 256 + tid;
      int row = f >> 3, c8 = f & 7;
      *(bf16x8*)((char*)lsA + row * 128 + ((c8 ^ (row & 7)) << 4)) = stA[i];
    }
#pragma unroll
    for (int i = 0; i < 2; ++i) {
      int f = i * 256 + tid;
      int row = f >> 3, c8 = f & 7;
      *(bf16x8*)((char*)lsB + row * 128 + ((c8 ^ (row & 7)) << 4)) = stB[i];
    }
  };

  f32x4 acc[2][4];
  f32x4 zero = {0.f, 0.f, 0.f, 0.f};
#pragma unroll
  for (int mi = 0; mi < 2; ++mi)
#pragma unroll
    for (int ni = 0; ni < 4; ++ni) acc[mi][ni] = zero;

  LOAD(0);
  WRITE();
  __syncthreads();

  for (int ks = 0; ks < 6; ++ks) {
    bf16x8 afr[2][2], bfr[4][2];
#pragma unroll
    for (int mi = 0; mi < 2; ++mi)
#pragma unroll
      for (int ku = 0; ku < 2; ++ku) {
        int row = wid * 32 + mi * 16 + rl;
        afr[mi][ku] = *(const bf16x8*)((char*)lsA + row * 128 +
                                       ((((ku << 2) | g) ^ (rl & 7)) << 4));
      }
#pragma unroll
    for (int ni = 0; ni < 4; ++ni)
#pragma unroll
      for (int ku = 0; ku < 2; ++ku) {
        int row = ni * 16 + rl;
        bfr[ni][ku] = *(const bf16x8*)((char*)lsB + row * 128 +
                                       ((((ku << 2) | g) ^ (rl & 7)) << 4));
      }
    if (ks < 5) LOAD(ks + 1);
    __syncthreads();
    if (ks < 5) WRITE();
#pragma unroll
    for (int ku = 0; ku < 2; ++ku)
#pragma unroll
      for (int mi = 0; mi < 2; ++mi)
#pragma unroll
        for (int ni = 0; ni < 4; ++ni)
          acc[mi][ni] = MFMA_B16(afr[mi][ku], bfr[ni][ku], acc[mi][ni]);
    __syncthreads();
  }

#pragma unroll
  for (int mi = 0; mi < 2; ++mi)
#pragma unroll
    for (int ni = 0; ni < 4; ++ni) {
      int c0 = wid * 32 + mi * 16 + g * 4;
      int w  = n0 + ni * 16 + rl;
#pragma unroll
      for (int q = 0; q < 4; ++q)
        h[((int64_t)(b * 128 + c0 + q) << 10) + w] = acc[mi][ni][q] + bias[c0 + q];
    }
}

// ---------------- Kernel 6: fused BN stats + apply + output permutation ----------------
__global__ __launch_bounds__(256) void k_statsout(const float* __restrict__ hpre,
                                                  const float* __restrict__ gamma,
                                                  const float* __restrict__ beta,
                                                  float* __restrict__ out) {
  const int o = blockIdx.x;
  const int tid = threadIdx.x;
  float s = 0.f, s2 = 0.f;
  for (int e = tid; e < 8192; e += 256) {
    int bb = e >> 10, v = e & 1023;
    float val = hpre[((int64_t)(bb * 128 + o) << 10) + v];
    s += val;
    s2 = fmaf(val, val, s2);
  }
#pragma unroll
  for (int off = 1; off < 64; off <<= 1) {
    s  += __shfl_xor(s, off, 64);
    s2 += __shfl_xor(s2, off, 64);
  }
  __shared__ float rs[4], rs2[4];
  __shared__ float scsh[2];
  int lane = tid & 63, wid = tid >> 6;
  if (lane == 0) { rs[wid] = s; rs2[wid] = s2; }
  __syncthreads();
  if (tid == 0) {
    float S  = rs[0] + rs[1] + rs[2] + rs[3];
    float S2 = rs2[0] + rs2[1] + rs2[2] + rs2[3];
    float mean = S * (1.0f / 8192.0f);
    float var  = S2 * (1.0f / 8192.0f) - mean * mean;
    float istd = rsqrtf(var + 1e-5f);
    float scale = gamma[o] * istd;
    scsh[0] = scale;
    scsh[1] = beta[o] - mean * scale;
  }
  __syncthreads();
  const float sc = scsh[0], sh = scsh[1];
  for (int q = tid; q < 8192; q += 256) {
    int b  = q >> 10;
    int pd = q & 1023;
    int p  = pd >> 9;
    int d  = pd & 511;
    float val = hpre[(((int64_t)(b * 128 + o)) << 10) + 2 * d + p];
    out[(((int64_t)(b * 256 + p * 128 + o)) << 9) + d] = fmaf(val, sc, sh);
  }
}

extern "C" void kernel_launch(void* const* d_in, const int* in_sizes, int n_in,
                              void* d_out, int out_size, void* d_ws, size_t ws_size,
                              hipStream_t stream) {
  const float* x     = (const float*)d_in[0];
  const float* dx    = (const float*)d_in[1];
  const float* W     = (const float*)d_in[2];
  const float* cb    = (const float*)d_in[3];
  const float* gamma = (const float*)d_in[4];
  const float* beta  = (const float*)d_in[5];

  char* ws = (char*)d_ws;
  bf16*   XcatT = (bf16*)(ws);                    //  6,291,456 B  [8][1024][384]
  bf16*   AT    = (bf16*)(ws + 6291456);          // 16,777,216 B  [8][1024][1024]
  bf16*   pvb   = (bf16*)(ws + 23068672);         //  2,097,152 B  [8][128][1024]
  bf16*   x1b   = (bf16*)(ws + 25165824);         //  2,097,152 B  [8][128][1024]
  float*  h     = (float*)(ws + 27361280);        //  4,194,304 B  [8][128][1024]
  float* out    = (float*)d_out;

  k_pool<<<8192, 256, 0, stream>>>(x, dx, pvb);
  k_tr<<<256, 256, 0, stream>>>(pvb, XcatT);
  k_adj<<<512, 256, 0, stream>>>(XcatT, AT);
  k_gemm<1, 128><<<128, 256, 0, stream>>>(pvb, AT, x1b, XcatT);
  k_gemm<0, 256><<<128, 256, 0, stream>>>(x1b, AT, nullptr, XcatT);
  k_conv<<<128, 256, 0, stream>>>(W, XcatT, cb, h);
  k_statsout<<<128, 256, 0, stream>>>(h, gamma, beta, out);
}